// Round 11
// baseline (189.160 us; speedup 1.0000x reference)
//
#include <hip/hip_runtime.h>

typedef float f32x2 __attribute__((ext_vector_type(2)));
typedef float f32x4 __attribute__((ext_vector_type(4)));

#define NN 16384
#define NCB 8
#define DIM 32
#define CB 1024
#define RPB 512  // rows per block (one k)

__device__ __forceinline__ void gload_lds16(const void* g, void* l) {
    __builtin_amdgcn_global_load_lds(
        (const __attribute__((address_space(1))) unsigned int*)g,
        (__attribute__((address_space(3))) unsigned int*)l, 16, 0, 0);
}

// packed 2xFP32 FMA; each half bit-identical to scalar fmaf (frozen chain).
__device__ __forceinline__ f32x2 pkfma(f32x2 a, f32x2 b, f32x2 c) {
    f32x2 d = c;
    asm("v_pk_fma_f32 %0, %1, %2, %0" : "+v"(d) : "v"(a), "v"(b));
    return d;
}

// Kernel A: csqb[k*CB+c] = ||codebook[k,c]||^2 + rate_bias[k,c]
__global__ __launch_bounds__(256) void vq_csq(const float* __restrict__ cb,
                                              const float* __restrict__ rb,
                                              float* __restrict__ out) {
    int i = blockIdx.x * 256 + threadIdx.x;
    if (i >= NCB * CB) return;
    const float4* c4 = reinterpret_cast<const float4*>(cb + (size_t)i * DIM);
    float s0 = 0.f, s1 = 0.f, s2 = 0.f, s3 = 0.f;
#pragma unroll
    for (int j = 0; j < 8; ++j) {
        float4 v = c4[j];
        s0 = fmaf(v.x, v.x, s0);
        s1 = fmaf(v.y, v.y, s1);
        s2 = fmaf(v.z, v.z, s2);
        s3 = fmaf(v.w, v.w, s3);
    }
    out[i] = ((s0 + s1) + (s2 + s3)) + rb[i];
}

// Fused kernel: 256 blocks (1/CU, 144 KB LDS) x 512 threads (8 waves, 2/SIMD).
// ENTIRE k-slice of the codebook (128 KB) staged to LDS in the prologue ->
// the main loop has ZERO VMEM loads. Its vmcnt FIFO holds only the paced
// one_hot zero-stores (1 store-instr per entry), which are never waited on
// until the single post-scan __syncthreads: true background drain under the
// LDS-bound scan. Wave (rh,q) scans quarter q for row-half rh, 4 rows/thread
// (R8 layout). A-operand read in two 4-reg halves (VGPR ~200, no spill).
// Frozen pk_fma chain (bit-identical to R10, which passed absmax 0).
__global__ __launch_bounds__(512, 2) void vq_fused(
    const float* __restrict__ x, const float* __restrict__ cb,
    const float* __restrict__ csqb, float* __restrict__ xhat,
    float* __restrict__ onehot, float* __restrict__ idxf) {
    __shared__ f32x4 cbL[CB * 8];  // 128 KB: whole codebook slice for this k
    __shared__ float pd[4][RPB];   // 8 KB
    __shared__ int pi[4][RPB];     // 8 KB -> 144 KB total: 1 block/CU

    const int tid = threadIdx.x;
    const int w = tid >> 6;
    const int lane = tid & 63;
    const int rh = w >> 2;  // row half
    const int q = w & 3;    // codebook quarter
    const int k = blockIdx.x & (NCB - 1);
    const int n0 = (blockIdx.x >> 3) * RPB;

    const f32x4* cbk4 =
        reinterpret_cast<const f32x4*>(cb + (size_t)k * CB * DIM);
    const float* cqk = csqb + (size_t)k * CB;

    // ---- prologue: stage whole codebook slice (8192 f32x4, 16/thread) ----
#pragma unroll
    for (int j = 0; j < 16; ++j)
        gload_lds16(cbk4 + j * 512 + tid, &cbL[j * 512 + tid]);

    // ---- 4 x-rows -> registers as pk pairs; ||x||^2 (frozen chain) ----
    const int rbase = rh * 256 + lane * 4;
    f32x2 xlo[4][8], xhi[4][8];
    float xsq[4];
#pragma unroll
    for (int j = 0; j < 4; ++j) {
        const int n = n0 + rbase + j;
        const f32x4* xp =
            reinterpret_cast<const f32x4*>(x + ((size_t)n * NCB + k) * DIM);
        f32x4 xt[8];
#pragma unroll
        for (int jj = 0; jj < 8; ++jj) xt[jj] = xp[jj];
        float q0 = 0.f, q1 = 0.f, q2 = 0.f, q3 = 0.f;
#pragma unroll
        for (int jj = 0; jj < 8; ++jj) {
            q0 = fmaf(xt[jj].x, xt[jj].x, q0);
            q1 = fmaf(xt[jj].y, xt[jj].y, q1);
            q2 = fmaf(xt[jj].z, xt[jj].z, q2);
            q3 = fmaf(xt[jj].w, xt[jj].w, q3);
        }
        xsq[j] = (q0 + q1) + (q2 + q3);
#pragma unroll
        for (int jj = 0; jj < 8; ++jj) {
            xlo[j][jj] = __builtin_shufflevector(xt[jj], xt[jj], 0, 1);
            xhi[j][jj] = __builtin_shufflevector(xt[jj], xt[jj], 2, 3);
        }
    }

    const int qbase = q * 256;
    // quarter's cq -> 4 regs (statically indexed via unrolled group loop)
    float cqall[4];
#pragma unroll
    for (int i = 0; i < 4; ++i) cqall[i] = cqk[qbase + i * 64 + lane];

    __syncthreads();  // codebook resident; prologue loads drained (no stores yet)

    float best[4];
    int bi[4];
#pragma unroll
    for (int j = 0; j < 4; ++j) {
        best[j] = 3.4028235e38f;
        bi[j] = 0;
    }

    float4* oh4 = reinterpret_cast<float4*>(onehot);
    const float4 z4 = make_float4(0.f, 0.f, 0.f, 0.f);

    // ---- main scan: 4 groups x 64 entries; zero loads, paced stores ----
#pragma unroll
    for (int g = 0; g < 4; ++g) {
        const float cql = cqall[g];
#pragma unroll 2
        for (int cc = 0; cc < 64; ++cc) {
            const int ce = g * 64 + cc;   // entry index within quarter
            const int c = qbase + ce;     // global entry index

            // paced zero-fill: wave w owns rows [w*64,+64), 4 stores/row
            {
                const int zrow = n0 + w * 64 + (ce >> 2);
                oh4[((size_t)zrow * NCB + k) * 256 + (ce & 3) * 64 + lane] = z4;
            }

            const float cqv = __int_as_float(
                __builtin_amdgcn_readlane(__float_as_int(cql), cc));

            f32x2 acc01[4], acc23[4];
#pragma unroll
            for (int j = 0; j < 4; ++j) {
                acc01[j] = (f32x2){0.f, 0.f};
                acc23[j] = (f32x2){0.f, 0.f};
            }
            // first half of the entry (A[0..3])
#pragma unroll
            for (int jj = 0; jj < 4; ++jj) {
                const f32x4 A = cbL[(size_t)c * 8 + jj];
                const f32x2 alo = __builtin_shufflevector(A, A, 0, 1);
                const f32x2 ahi = __builtin_shufflevector(A, A, 2, 3);
#pragma unroll
                for (int j = 0; j < 4; ++j) {
                    acc01[j] = pkfma(xlo[j][jj], alo, acc01[j]);
                    acc23[j] = pkfma(xhi[j][jj], ahi, acc23[j]);
                }
            }
            // second half (A[4..7]) — per-j chain stays jj-ascending
#pragma unroll
            for (int jj = 4; jj < 8; ++jj) {
                const f32x4 A = cbL[(size_t)c * 8 + jj];
                const f32x2 alo = __builtin_shufflevector(A, A, 0, 1);
                const f32x2 ahi = __builtin_shufflevector(A, A, 2, 3);
#pragma unroll
                for (int j = 0; j < 4; ++j) {
                    acc01[j] = pkfma(xlo[j][jj], alo, acc01[j]);
                    acc23[j] = pkfma(xhi[j][jj], ahi, acc23[j]);
                }
            }
#pragma unroll
            for (int j = 0; j < 4; ++j) {
                const float dot =
                    (acc01[j].x + acc01[j].y) + (acc23[j].x + acc23[j].y);
                const float dist = fmaf(-2.f, dot, xsq[j] + cqv);
                if (dist < best[j]) {  // strict <: first occurrence in quarter
                    best[j] = dist;
                    bi[j] = c;
                }
            }
        }
    }

    // ---- publish per-quarter partials ----
#pragma unroll
    for (int j = 0; j < 4; ++j) {
        pd[q][rbase + j] = best[j];
        pi[q][rbase + j] = bi[j];
    }
    __syncthreads();  // partials visible + ALL zero-stores drained (vmcnt 0)

    // ---- combine quarters + outputs; thread tid owns block-row tid ----
    {
        const int r = tid;
        float bd = pd[0][r];
        int bx = pi[0][r];
#pragma unroll
        for (int qq = 1; qq < 4; ++qq) {
            const float dq = pd[qq][r];
            const int iq = pi[qq][r];
            // ascending quarters => on tie keep lower (earlier) index
            if (dq < bd) {
                bd = dq;
                bx = iq;
            }
        }
        const int n = n0 + r;
        idxf[(size_t)n * NCB + k] = (float)bx;
        // x_hat gather from GLOBAL (post-barrier: store FIFO already drained;
        // LDS gather here would 16-way bank-conflict on the 128B stride)
        const f32x4* src = cbk4 + (size_t)bx * 8;
        f32x4* dst =
            reinterpret_cast<f32x4*>(xhat + ((size_t)n * NCB + k) * DIM);
#pragma unroll
        for (int jj = 0; jj < 8; ++jj) dst[jj] = src[jj];
        onehot[((size_t)n * NCB + k) * CB + bx] = 1.0f;
    }
}

extern "C" void kernel_launch(void* const* d_in, const int* in_sizes, int n_in,
                              void* d_out, int out_size, void* d_ws,
                              size_t ws_size, hipStream_t stream) {
    const float* x = (const float*)d_in[0];
    const float* cb = (const float*)d_in[1];
    const float* rb = (const float*)d_in[2];

    float* out = (float*)d_out;
    float* xhat = out;                             // N*NCB*DIM
    float* onehot = out + (size_t)NN * NCB * DIM;  // N*NCB*CB
    float* idxf = onehot + (size_t)NN * NCB * CB;  // N*NCB

    float* csqb = (float*)d_ws;  // NCB*CB floats = 32 KB

    vq_csq<<<(NCB * CB + 255) / 256, 256, 0, stream>>>(cb, rb, csqb);
    vq_fused<<<(NN / RPB) * NCB, 512, 0, stream>>>(x, cb, csqb, xhat, onehot,
                                                   idxf);
}